// Round 6
// baseline (46.017 us; speedup 1.0000x reference)
//
#include <hip/hip_runtime.h>
#include <math.h>

#define NDB 32
#define DMIN 0.5f
#define DMAX 15.0f
#define VV 4
#define CC 32
#define HH 128
#define WW 160
#define HWHW (HH*WW)
#define CONST_FLOATS 128
#define NXCD 8

typedef float f2 __attribute__((ext_vector_type(2)));

#if defined(__has_builtin)
#  if __has_builtin(__builtin_amdgcn_cvt_pk_f32_fp8) && __has_builtin(__builtin_amdgcn_cvt_pk_fp8_f32)
#    define HW_FP8 1
#  endif
#endif

#ifdef HW_FP8
__device__ __forceinline__ f2 cvt2lo(unsigned int w) {
    return __builtin_amdgcn_cvt_pk_f32_fp8((int)w, false);
}
__device__ __forceinline__ f2 cvt2hi(unsigned int w) {
    return __builtin_amdgcn_cvt_pk_f32_fp8((int)w, true);
}
__device__ __forceinline__ unsigned int pk8(float a, float b, float c, float d) {
    int x = 0;
    x = __builtin_amdgcn_cvt_pk_fp8_f32(a, b, x, false);
    x = __builtin_amdgcn_cvt_pk_fp8_f32(c, d, x, true);
    return (unsigned int)x;
}
#else
// Software OCP e4m3fn fallback (only used if the builtins are unavailable).
__device__ __forceinline__ float dec8(unsigned int b) {
    unsigned s = (b >> 7) & 1, e = (b >> 3) & 15, m = b & 7;
    float v;
    if (e == 0) v = ldexpf((float)m, -9);           // subnormal: m/8 * 2^-6
    else        v = ldexpf(1.0f + (float)m*0.125f, (int)e - 7);
    return s ? -v : v;
}
__device__ __forceinline__ unsigned int enc8(float f) {
    unsigned s = (f < 0.0f) ? 0x80u : 0u;
    f = fabsf(f);
    if (!(f == f)) return 0x7Fu;
    f = fminf(f, 448.0f);
    if (f < ldexpf(1.0f, -9)) return s;             // underflow to 0
    int e; float m = frexpf(f, &e);                 // f = m*2^e, m in [0.5,1)
    // normal: f = (1+frac)*2^(e-1); e8 = e-1+7
    int e8 = e - 1 + 7;
    unsigned mant;
    if (e8 <= 0) {                                  // subnormal
        float q = ldexpf(f, 9);                     // f / 2^-9
        mant = (unsigned)(q + 0.5f);
        if (mant > 7) { mant = 0; e8 = 1; }
        return s | ((unsigned)e8 << 3) | mant;      // e8==0 path encodes mant only
    }
    float frac = m * 2.0f - 1.0f;                   // [0,1)
    mant = (unsigned)(frac * 8.0f + 0.5f);
    if (mant > 7) { mant = 0; e8 += 1; }
    if (e8 > 15) { e8 = 15; mant = 6; }             // clamp below nan
    return s | ((unsigned)e8 << 3) | mant;
}
__device__ __forceinline__ f2 cvt2lo(unsigned int w) {
    return (f2){dec8(w & 255u), dec8((w >> 8) & 255u)};
}
__device__ __forceinline__ f2 cvt2hi(unsigned int w) {
    return (f2){dec8((w >> 16) & 255u), dec8((w >> 24) & 255u)};
}
__device__ __forceinline__ unsigned int pk8(float a, float b, float c, float d) {
    return enc8(a) | (enc8(b) << 8) | (enc8(c) << 16) | (enc8(d) << 24);
}
#endif

// ws layout:
// [0..CONST_FLOATS) floats: Kinv (0..8); per view v (base=16+v*16): M[0..8],
//   b[9..11], fx=12, fy=13, cx=14, cy=15
// then srcT: V*HW*32 bytes fp8 (V,HW,C)
// then refT: HW*32 floats, normalized (HW,C)
__device__ __forceinline__ void do_setup(const float* __restrict__ K_ref,
                                         const float* __restrict__ c2w_ref,
                                         const float* __restrict__ K_srcs,
                                         const float* __restrict__ c2w_srcs,
                                         float* __restrict__ cw) {
    float a00=K_ref[0], a01=K_ref[1], a02=K_ref[2];
    float a10=K_ref[3], a11=K_ref[4], a12=K_ref[5];
    float a20=K_ref[6], a21=K_ref[7], a22=K_ref[8];
    float det = a00*(a11*a22-a12*a21) - a01*(a10*a22-a12*a20) + a02*(a10*a21-a11*a20);
    float id = 1.0f/det;
    cw[0] = (a11*a22-a12*a21)*id;
    cw[1] = (a02*a21-a01*a22)*id;
    cw[2] = (a01*a12-a02*a11)*id;
    cw[3] = (a12*a20-a10*a22)*id;
    cw[4] = (a00*a22-a02*a20)*id;
    cw[5] = (a02*a10-a00*a12)*id;
    cw[6] = (a10*a21-a11*a20)*id;
    cw[7] = (a01*a20-a00*a21)*id;
    cw[8] = (a00*a11-a01*a10)*id;

    float Rr[9], tr[3];
    for (int i=0;i<3;i++){ for (int j=0;j<3;j++) Rr[i*3+j]=c2w_ref[i*4+j]; tr[i]=c2w_ref[i*4+3]; }

    for (int v=0; v<VV; v++) {
        const float* P = c2w_srcs + v*16;
        float Rv[9], tv[3];
        for (int i=0;i<3;i++){ for (int j=0;j<3;j++) Rv[i*3+j]=P[i*4+j]; tv[i]=P[i*4+3]; }
        float* o = cw + 16 + v*16;
        for (int i=0;i<3;i++) for (int j=0;j<3;j++) {
            float s = 0.f;
            for (int k=0;k<3;k++) s += Rv[k*3+i]*Rr[k*3+j];
            o[i*3+j] = s;
        }
        float dt0 = tr[0]-tv[0], dt1 = tr[1]-tv[1], dt2 = tr[2]-tv[2];
        for (int i=0;i<3;i++) {
            o[9+i] = Rv[0*3+i]*dt0 + Rv[1*3+i]*dt1 + Rv[2*3+i]*dt2;
        }
        const float* Ks = K_srcs + v*9;
        o[12]=Ks[0]; o[13]=Ks[4]; o[14]=Ks[2]; o[15]=Ks[5];
    }
}

// Fused prepass: src (V,C,HW) f32 -> (V,HW,C) fp8; ref (C,HW) f32 ->
// normalized (HW,C) f32; pose setup on thread 0.
__global__ __launch_bounds__(256) void prepass(const float* __restrict__ src,
                                               const float* __restrict__ ref,
                                               const float* __restrict__ K_ref,
                                               const float* __restrict__ c2w_ref,
                                               const float* __restrict__ K_srcs,
                                               const float* __restrict__ c2w_srcs,
                                               unsigned char* __restrict__ srcT,
                                               float* __restrict__ refT,
                                               float* __restrict__ cw) {
    int gid = blockIdx.x * 256 + threadIdx.x;
    if (gid < VV*HWHW) {
        int v = gid / HWHW, n = gid % HWHW;
        const float* in = src + (size_t)v*CC*HWHW + n;
        float vals[CC];
        #pragma unroll
        for (int c=0; c<CC; c++) vals[c] = in[(size_t)c*HWHW];
        uint4 w0, w1;
        w0.x = pk8(vals[0],  vals[1],  vals[2],  vals[3]);
        w0.y = pk8(vals[4],  vals[5],  vals[6],  vals[7]);
        w0.z = pk8(vals[8],  vals[9],  vals[10], vals[11]);
        w0.w = pk8(vals[12], vals[13], vals[14], vals[15]);
        w1.x = pk8(vals[16], vals[17], vals[18], vals[19]);
        w1.y = pk8(vals[20], vals[21], vals[22], vals[23]);
        w1.z = pk8(vals[24], vals[25], vals[26], vals[27]);
        w1.w = pk8(vals[28], vals[29], vals[30], vals[31]);
        uint4* outp = (uint4*)(srcT + (size_t)gid*32);
        outp[0] = w0; outp[1] = w1;
    } else if (gid < (VV+1)*HWHW) {
        int n = gid - VV*HWHW;
        float vals[CC];
        float ss = 0.f;
        #pragma unroll
        for (int c=0; c<CC; c++) { float x = ref[(size_t)c*HWHW + n]; vals[c]=x; ss += x*x; }
        float inv = 1.0f / fmaxf(sqrtf(ss), 1e-12f);
        float4* outp = (float4*)(refT + (size_t)n*CC);
        #pragma unroll
        for (int cc=0; cc<8; cc++) {
            outp[cc] = make_float4(vals[cc*4+0]*inv, vals[cc*4+1]*inv,
                                   vals[cc*4+2]*inv, vals[cc*4+3]*inv);
        }
    }
    if (gid == 0) do_setup(K_ref, c2w_ref, K_srcs, c2w_srcs, cw);
}

// Main kernel: QUAD-per-pixel, fp8 features. Lane j of a quad holds channels
// [8j..8j+8) = 8 bytes of the pixel's 32B fp8 line; a wave's 16 pixels x 32B
// chunks coalesce, and adjacent projected pixels pair into single 64B lines
// (halves TCP line requests vs fp16). 2 depths per thread, XCD-swizzled strips.
__global__ __launch_bounds__(256, 4) void cost_volume_quad(
        const unsigned char* __restrict__ srcp,  // (V,HW,C) fp8
        const float* __restrict__ refp,          // (HW,C) f32 normalized
        const float* __restrict__ cw,
        float* __restrict__ out) {
    int b = blockIdx.x;
    int xcd = b & (NXCD-1);
    int t = b >> 3;            // 0..639
    int dp = t & 15;           // depth-pair id
    int sHigh = t >> 4;        // 0..39
    int s = xcd + NXCD*sHigh;  // strip 0..319 (64 pixels each)
    int j = threadIdx.x & 3;   // chunk id within pixel
    int q = threadIdx.x >> 2;  // pixel within strip
    int n = s*64 + q;

    // this lane's ref channels (8 f32, 32B, quad-contiguous -> coalesced)
    f2 r2[4];
    {
        const float4* rp = (const float4*)(refp + (size_t)n*CC + j*8);
        float4 ra = rp[0], rb = rp[1];
        r2[0] = (f2){ra.x, ra.y}; r2[1] = (f2){ra.z, ra.w};
        r2[2] = (f2){rb.x, rb.y}; r2[3] = (f2){rb.z, rb.w};
    }

    int ix = n % WW, iy = n / WW;
    float px = (float)ix, py = (float)iy;

    float rx = cw[0]*px + cw[1]*py + cw[2];
    float ry = cw[3]*px + cw[4]*py + cw[5];
    float rz = cw[6]*px + cw[7]*py + cw[8];

    // depth-independent per-view ray rotation
    float mxa[VV], mya[VV], mza[VV];
    #pragma unroll
    for (int v=0; v<VV; v++) {
        const float* o = cw + 16 + v*16;
        mxa[v] = o[0]*rx + o[1]*ry + o[2]*rz;
        mya[v] = o[3]*rx + o[4]*ry + o[5]*rz;
        mza[v] = o[6]*rx + o[7]*ry + o[8]*rz;
    }

    const float invmin = 1.0f/DMAX;
    const float step = (1.0f/DMIN - 1.0f/DMAX) / (float)(NDB-1);

    #pragma unroll
    for (int dd=0; dd<2; dd++) {
        int d = dp*2 + dd;
        float invd = invmin + step * (float)d;
        float zthr = 1e-6f * invd;   // Zraw>1e-6  <=>  az>zthr (az = Zraw*invd)

        // ---- geometry for all views ----
        float w00a[VV], w10a[VV], w01a[VV], w11a[VV], vmask[VV];
        int   i00a[VV], i10a[VV], i01a[VV], i11a[VV];
        #pragma unroll
        for (int v=0; v<VV; v++) {
            const float* o = cw + 16 + v*16;
            float ax = fmaf(o[9],  invd, mxa[v]);
            float ay = fmaf(o[10], invd, mya[v]);
            float az = fmaf(o[11], invd, mza[v]);
            float azc = fmaxf(az, zthr);
            float zr = __builtin_amdgcn_rcpf(azc);
            float u  = fmaf(o[12], ax*zr, o[14]);
            float vv = fmaf(o[13], ay*zr, o[15]);
            vmask[v] = ((u >= 0.0f) && (u <= (float)(WW-1)) &&
                        (vv >= 0.0f) && (vv <= (float)(HH-1)) && (az > zthr)) ? 1.0f : 0.0f;

            float x0f = floorf(u), y0f = floorf(vv);
            float wx1 = u - x0f,  wy1 = vv - y0f;
            float wx0 = 1.0f - wx1, wy0 = 1.0f - wy1;
            int x0 = (int)x0f, y0 = (int)y0f;
            int cx0 = min(max(x0,0),WW-1),   cx1 = min(max(x0+1,0),WW-1);
            int cy0 = min(max(y0,0),HH-1),   cy1 = min(max(y0+1,0),HH-1);
            w00a[v] = wx0*wy0; w10a[v] = wx1*wy0;
            w01a[v] = wx0*wy1; w11a[v] = wx1*wy1;
            i00a[v] = cy0*WW+cx0; i10a[v] = cy0*WW+cx1;
            i01a[v] = cy1*WW+cx0; i11a[v] = cy1*WW+cx1;
        }

        // ---- all 16 gathers (8B each) in flight ----
        uint2 g00[VV], g10[VV], g01[VV], g11[VV];
        #pragma unroll
        for (int v=0; v<VV; v++) {
            const uint2* bp = (const uint2*)(srcp + (size_t)v*HWHW*32) + j;
            g00[v] = bp[(size_t)i00a[v]*4];
            g10[v] = bp[(size_t)i10a[v]*4];
            g01[v] = bp[(size_t)i01a[v]*4];
            g11[v] = bp[(size_t)i11a[v]*4];
        }

        // ---- unpack + blend (packed f32) + dot/norm ----
        float dtv[VV], nmv[VV];
        #pragma unroll
        for (int v=0; v<VV; v++) {
            float w00 = w00a[v], w10 = w10a[v], w01 = w01a[v], w11 = w11a[v];
            f2 d2 = {0.f, 0.f}, n2 = {0.f, 0.f};
            f2 a;
            a = cvt2lo(g00[v].x)*w00 + cvt2lo(g10[v].x)*w10
              + cvt2lo(g01[v].x)*w01 + cvt2lo(g11[v].x)*w11;
            d2 += r2[0]*a; n2 += a*a;
            a = cvt2hi(g00[v].x)*w00 + cvt2hi(g10[v].x)*w10
              + cvt2hi(g01[v].x)*w01 + cvt2hi(g11[v].x)*w11;
            d2 += r2[1]*a; n2 += a*a;
            a = cvt2lo(g00[v].y)*w00 + cvt2lo(g10[v].y)*w10
              + cvt2lo(g01[v].y)*w01 + cvt2lo(g11[v].y)*w11;
            d2 += r2[2]*a; n2 += a*a;
            a = cvt2hi(g00[v].y)*w00 + cvt2hi(g10[v].y)*w10
              + cvt2hi(g01[v].y)*w01 + cvt2hi(g11[v].y)*w11;
            d2 += r2[3]*a; n2 += a*a;
            dtv[v] = d2.x + d2.y; nmv[v] = n2.x + n2.y;
        }

        // ---- batched quad reductions ----
        #pragma unroll
        for (int v=0; v<VV; v++) {
            dtv[v] += __shfl_xor(dtv[v], 1);
            nmv[v] += __shfl_xor(nmv[v], 1);
        }
        #pragma unroll
        for (int v=0; v<VV; v++) {
            dtv[v] += __shfl_xor(dtv[v], 2);
            nmv[v] += __shfl_xor(nmv[v], 2);
        }
        float cost = 0.f;
        #pragma unroll
        for (int v=0; v<VV; v++) {
            cost += vmask[v] * dtv[v] * __builtin_amdgcn_rsqf(fmaxf(nmv[v], 1e-24f));
        }

        if (j == 0)      out[(size_t)d*HWHW + n] = cost * (1.0f/(float)VV);
        else if (j == 1) out[(size_t)NDB*HWHW + (size_t)d*HWHW + n] = 1.0f / invd;
    }
}

// f32 fallback (no workspace): strided gathers from original layout.
__global__ __launch_bounds__(256) void cost_volume_fallback(
        const float* __restrict__ srcp,  // (V,C,HW)
        const float* __restrict__ refp,  // (C,HW)
        const float* __restrict__ cw,
        float* __restrict__ out) {
    int n = blockIdx.x * 256 + threadIdx.x;
    int d = blockIdx.y;
    if (n >= HWHW) return;
    float px = (float)(n % WW), py = (float)(n / WW);

    float rx = cw[0]*px + cw[1]*py + cw[2];
    float ry = cw[3]*px + cw[4]*py + cw[5];
    float rz = cw[6]*px + cw[7]*py + cw[8];

    const float invmin = 1.0f/DMAX;
    const float step = (1.0f/DMIN - 1.0f/DMAX) / (float)(NDB-1);
    float invd = invmin + step * (float)d;
    float depth = 1.0f / invd;

    float rf[CC];
    float ss = 0.f;
    #pragma unroll
    for (int c=0; c<CC; c++) { float x = refp[(size_t)c*HWHW + n]; rf[c]=x; ss += x*x; }
    float inv = 1.0f / fmaxf(sqrtf(ss), 1e-12f);
    #pragma unroll
    for (int c=0; c<CC; c++) rf[c] *= inv;

    float cost = 0.f;
    #pragma unroll
    for (int v=0; v<VV; v++) {
        const float* o = cw + 16 + v*16;
        float mx = o[0]*rx + o[1]*ry + o[2]*rz;
        float my = o[3]*rx + o[4]*ry + o[5]*rz;
        float mz = o[6]*rx + o[7]*ry + o[8]*rz;
        float X = depth*mx + o[9];
        float Y = depth*my + o[10];
        float Zraw = depth*mz + o[11];
        float Z = fmaxf(Zraw, 1e-6f);
        float u  = o[12]*(X/Z) + o[14];
        float vv = o[13]*(Y/Z) + o[15];
        float gx = 2.0f*(u/(float)(WW-1)) - 1.0f;
        float gy = 2.0f*(vv/(float)(HH-1)) - 1.0f;
        bool valid = (gx >= -1.0f) && (gx <= 1.0f) && (gy >= -1.0f) && (gy <= 1.0f) && (Zraw > 1e-6f);

        float x0f = floorf(u), y0f = floorf(vv);
        float wx1 = u - x0f,  wy1 = vv - y0f;
        float wx0 = 1.0f - wx1, wy0 = 1.0f - wy1;
        int x0 = (int)x0f, y0 = (int)y0f;
        int x1 = x0 + 1,   y1 = y0 + 1;

        float m00 = (x0>=0 && x0<WW && y0>=0 && y0<HH) ? 1.f : 0.f;
        float m10 = (x1>=0 && x1<WW && y0>=0 && y0<HH) ? 1.f : 0.f;
        float m01 = (x0>=0 && x0<WW && y1>=0 && y1<HH) ? 1.f : 0.f;
        float m11 = (x1>=0 && x1<WW && y1>=0 && y1<HH) ? 1.f : 0.f;
        float w00 = wx0*wy0*m00, w10 = wx1*wy0*m10;
        float w01 = wx0*wy1*m01, w11 = wx1*wy1*m11;

        int cx0 = min(max(x0,0),WW-1), cx1 = min(max(x1,0),WW-1);
        int cy0 = min(max(y0,0),HH-1), cy1 = min(max(y1,0),HH-1);
        int i00 = cy0*WW+cx0, i10 = cy0*WW+cx1;
        int i01 = cy1*WW+cx0, i11 = cy1*WW+cx1;

        float dot = 0.f, nrm = 0.f;
        const float* basep = srcp + (size_t)v*CC*HWHW;
        #pragma unroll
        for (int c=0; c<CC; c++) {
            const float* pc = basep + (size_t)c*HWHW;
            float wcv = w00*pc[i00] + w10*pc[i10] + w01*pc[i01] + w11*pc[i11];
            dot += rf[c]*wcv;
            nrm += wcv*wcv;
        }
        float sim = dot / fmaxf(sqrtf(nrm), 1e-12f);
        cost += valid ? sim : 0.f;
    }

    out[(size_t)d*HWHW + n] = cost * (1.0f/(float)VV);
    out[(size_t)NDB*HWHW + (size_t)d*HWHW + n] = depth;
}

extern "C" void kernel_launch(void* const* d_in, const int* in_sizes, int n_in,
                              void* d_out, int out_size, void* d_ws, size_t ws_size,
                              hipStream_t stream) {
    const float* ref_feat  = (const float*)d_in[0];
    const float* src_feats = (const float*)d_in[1];
    const float* K_ref     = (const float*)d_in[2];
    const float* c2w_ref   = (const float*)d_in[3];
    const float* K_srcs    = (const float*)d_in[4];
    const float* c2w_srcs  = (const float*)d_in[5];
    float* out = (float*)d_out;
    float* ws  = (float*)d_ws;

    size_t need_bytes = (size_t)CONST_FLOATS*sizeof(float)
                      + (size_t)VV*HWHW*32                 // srcT fp8
                      + (size_t)HWHW*CC*sizeof(float);     // refT f32

    if (ws_size >= need_bytes) {
        unsigned char* srcT = (unsigned char*)(ws + CONST_FLOATS);
        float* refT = (float*)(srcT + (size_t)VV*HWHW*32);
        prepass<<<((VV+1)*HWHW + 255)/256, 256, 0, stream>>>(
            src_feats, ref_feat, K_ref, c2w_ref, K_srcs, c2w_srcs, srcT, refT, ws);
        // 320 strips x 16 depth-pairs, XCD-swizzled
        cost_volume_quad<<<(HWHW/64)*(NDB/2), 256, 0, stream>>>(srcT, refT, ws, out);
    } else {
        prepass<<<1, 1, 0, stream>>>(
            src_feats, ref_feat, K_ref, c2w_ref, K_srcs, c2w_srcs,
            (unsigned char*)ws, ws, ws);  // only gid==0 setup matters
        dim3 grid(HWHW/256, NDB);
        cost_volume_fallback<<<grid, 256, 0, stream>>>(src_feats, ref_feat, ws, out);
    }
}

// Round 8
// 41.044 us; speedup vs baseline: 1.1212x; 1.1212x over previous
//
#include <hip/hip_runtime.h>
#include <math.h>

#define NDB 32
#define DMIN 0.5f
#define DMAX 15.0f
#define VV 4
#define CC 32
#define HH 128
#define WW 160
#define HWHW (HH*WW)
#define CONST_FLOATS 128
#define NXCD 8
#define DPT 4   // depths per thread

typedef _Float16 h8 __attribute__((ext_vector_type(8)));
typedef _Float16 h2 __attribute__((ext_vector_type(2)));

#if defined(__has_builtin)
#  if __has_builtin(__builtin_amdgcn_fdot2)
#    define FDOT2(a,b,c) __builtin_amdgcn_fdot2((a),(b),(c),false)
#  endif
#endif
#ifndef FDOT2
#  define FDOT2(a,b,c) ((c) + (float)(a)[0]*(float)(b)[0] + (float)(a)[1]*(float)(b)[1])
#endif

__device__ __forceinline__ h2 get2(h8 x, int i) {
    // i is compile-time under full unroll; pair i occupies one VGPR of x
    return (h2){x[2*i], x[2*i+1]};
}
__device__ __forceinline__ h2 bcast_h2(float w) {
#if defined(__has_builtin) && __has_builtin(__builtin_amdgcn_cvt_pkrtz)
    auto r = __builtin_amdgcn_cvt_pkrtz(w, w);   // __fp16 ext_vector(2)
    h2 out;
    __builtin_memcpy(&out, &r, sizeof(out));     // same bits, zero-cost
    return out;
#else
    _Float16 h = (_Float16)w; return (h2){h, h};
#endif
}

// ws float layout:
// [0..8]  Kinv of K_ref
// per view v (base = 16 + v*16): M[0..8] (= Rv^T Rref), b[9..11] (= Rv^T (t_ref - t_v)),
//                                fx=12, fy=13, cx=14, cy=15
__device__ __forceinline__ void do_setup(const float* __restrict__ K_ref,
                                         const float* __restrict__ c2w_ref,
                                         const float* __restrict__ K_srcs,
                                         const float* __restrict__ c2w_srcs,
                                         float* __restrict__ cw) {
    float a00=K_ref[0], a01=K_ref[1], a02=K_ref[2];
    float a10=K_ref[3], a11=K_ref[4], a12=K_ref[5];
    float a20=K_ref[6], a21=K_ref[7], a22=K_ref[8];
    float det = a00*(a11*a22-a12*a21) - a01*(a10*a22-a12*a20) + a02*(a10*a21-a11*a20);
    float id = 1.0f/det;
    cw[0] = (a11*a22-a12*a21)*id;
    cw[1] = (a02*a21-a01*a22)*id;
    cw[2] = (a01*a12-a02*a11)*id;
    cw[3] = (a12*a20-a10*a22)*id;
    cw[4] = (a00*a22-a02*a20)*id;
    cw[5] = (a02*a10-a00*a12)*id;
    cw[6] = (a10*a21-a11*a20)*id;
    cw[7] = (a01*a20-a00*a21)*id;
    cw[8] = (a00*a11-a01*a10)*id;

    float Rr[9], tr[3];
    for (int i=0;i<3;i++){ for (int j=0;j<3;j++) Rr[i*3+j]=c2w_ref[i*4+j]; tr[i]=c2w_ref[i*4+3]; }

    for (int v=0; v<VV; v++) {
        const float* P = c2w_srcs + v*16;
        float Rv[9], tv[3];
        for (int i=0;i<3;i++){ for (int j=0;j<3;j++) Rv[i*3+j]=P[i*4+j]; tv[i]=P[i*4+3]; }
        float* o = cw + 16 + v*16;
        for (int i=0;i<3;i++) for (int j=0;j<3;j++) {
            float s = 0.f;
            for (int k=0;k<3;k++) s += Rv[k*3+i]*Rr[k*3+j];
            o[i*3+j] = s;
        }
        float dt0 = tr[0]-tv[0], dt1 = tr[1]-tv[1], dt2 = tr[2]-tv[2];
        for (int i=0;i<3;i++) {
            o[9+i] = Rv[0*3+i]*dt0 + Rv[1*3+i]*dt1 + Rv[2*3+i]*dt2;
        }
        const float* Ks = K_srcs + v*9;
        o[12]=Ks[0]; o[13]=Ks[4]; o[14]=Ks[2]; o[15]=Ks[5];
    }
}

// Fused prepass: src transpose (V,C,HW)->(V,HW,C) fp16, ref normalize+transpose
// (C,HW)->(HW,C) fp16, pose setup on thread 0.
__global__ __launch_bounds__(256) void prepass(const float* __restrict__ src,
                                               const float* __restrict__ ref,
                                               const float* __restrict__ K_ref,
                                               const float* __restrict__ c2w_ref,
                                               const float* __restrict__ K_srcs,
                                               const float* __restrict__ c2w_srcs,
                                               _Float16* __restrict__ srcT,
                                               _Float16* __restrict__ refT,
                                               float* __restrict__ cw) {
    int gid = blockIdx.x * 256 + threadIdx.x;
    if (gid < VV*HWHW) {
        int v = gid / HWHW, n = gid % HWHW;
        const float* in = src + (size_t)v*CC*HWHW + n;
        h8* outp = (h8*)(srcT + (size_t)gid*CC);
        #pragma unroll
        for (int cc=0; cc<4; cc++) {
            h8 t;
            #pragma unroll
            for (int j=0; j<8; j++)
                t[j] = (_Float16)in[(size_t)(cc*8+j)*HWHW];
            outp[cc] = t;
        }
    } else if (gid < (VV+1)*HWHW) {
        int n = gid - VV*HWHW;
        float vals[CC];
        float ss = 0.f;
        #pragma unroll
        for (int c=0; c<CC; c++) { float x = ref[(size_t)c*HWHW + n]; vals[c]=x; ss += x*x; }
        float inv = 1.0f / fmaxf(sqrtf(ss), 1e-12f);
        h8* outp = (h8*)(refT + (size_t)n*CC);
        #pragma unroll
        for (int cc=0; cc<4; cc++) {
            h8 t;
            #pragma unroll
            for (int j=0; j<8; j++) t[j] = (_Float16)(vals[cc*8+j]*inv);
            outp[cc] = t;
        }
    }
    if (gid == 0) do_setup(K_ref, c2w_ref, K_srcs, c2w_srcs, cw);
}

// Main kernel: QUAD-per-pixel, 4 depths/thread, fp16 features.
// All hot-loop addressing is 32-bit byte offsets against uniform SGPR bases
// (one v_lshl_add per gather) — no 64-bit address chains.
__global__ __launch_bounds__(256, 4) void cost_volume_quad(
        const _Float16* __restrict__ srcp,  // (V,HW,C) fp16
        const _Float16* __restrict__ refp,  // (HW,C) fp16 normalized
        const float* __restrict__ cw,
        float* __restrict__ out) {
    int b = blockIdx.x;
    int xcd = b & (NXCD-1);
    int t = b >> 3;            // 0..319
    int dq = t & 7;            // depth-quad id 0..7
    int sHigh = t >> 3;        // 0..39
    int s = xcd + NXCD*sHigh;  // strip 0..319 (64 pixels each)
    int j = threadIdx.x & 3;   // chunk id within pixel
    int q = threadIdx.x >> 2;  // pixel within strip
    int n = s*64 + q;
    int j16 = j*16;            // byte offset of this lane's 16B chunk

    // this lane's ref chunk (16B, quad-contiguous -> coalesced)
    h8 rfv = *(const h8*)((const char*)refp + (n*64 + j16));

    int ix = n % WW, iy = n / WW;
    float px = (float)ix, py = (float)iy;

    float rx = cw[0]*px + cw[1]*py + cw[2];
    float ry = cw[3]*px + cw[4]*py + cw[5];
    float rz = cw[6]*px + cw[7]*py + cw[8];

    // depth-independent per-view ray rotation + uniform byte bases
    float mxa[VV], mya[VV], mza[VV];
    const char* vbase[VV];
    #pragma unroll
    for (int v=0; v<VV; v++) {
        const float* o = cw + 16 + v*16;
        mxa[v] = o[0]*rx + o[1]*ry + o[2]*rz;
        mya[v] = o[3]*rx + o[4]*ry + o[5]*rz;
        mza[v] = o[6]*rx + o[7]*ry + o[8]*rz;
        vbase[v] = (const char*)srcp + (size_t)v*(HWHW*64);
    }

    const float invmin = 1.0f/DMAX;
    const float step = (1.0f/DMIN - 1.0f/DMAX) / (float)(NDB-1);

    #pragma unroll
    for (int dd=0; dd<DPT; dd++) {
        int d = dq*DPT + dd;
        float invd = invmin + step * (float)d;
        float zthr = 1e-6f * invd;   // Zraw>1e-6  <=>  az>zthr (az = Zraw*invd)

        // ---- geometry for all views (32-bit byte offsets) ----
        float w00a[VV], w10a[VV], w01a[VV], w11a[VV], vmask[VV];
        int   o00a[VV], o10a[VV], o01a[VV], o11a[VV];
        #pragma unroll
        for (int v=0; v<VV; v++) {
            const float* o = cw + 16 + v*16;
            float ax = fmaf(o[9],  invd, mxa[v]);
            float ay = fmaf(o[10], invd, mya[v]);
            float az = fmaf(o[11], invd, mza[v]);
            float azc = fmaxf(az, zthr);
            float zr = __builtin_amdgcn_rcpf(azc);
            float u  = fmaf(o[12], ax*zr, o[14]);
            float vv = fmaf(o[13], ay*zr, o[15]);
            vmask[v] = ((u >= 0.0f) && (u <= (float)(WW-1)) &&
                        (vv >= 0.0f) && (vv <= (float)(HH-1)) && (az > zthr)) ? 1.0f : 0.0f;

            float x0f = floorf(u), y0f = floorf(vv);
            float wx1 = u - x0f,  wy1 = vv - y0f;
            float wx0 = 1.0f - wx1, wy0 = 1.0f - wy1;
            int x0 = (int)x0f, y0 = (int)y0f;
            int cx0 = min(max(x0,0),WW-1),   cx1 = min(max(x0+1,0),WW-1);
            int cy0 = min(max(y0,0),HH-1),   cy1 = min(max(y0+1,0),HH-1);
            w00a[v] = wx0*wy0; w10a[v] = wx1*wy0;
            w01a[v] = wx0*wy1; w11a[v] = wx1*wy1;
            int r0 = cy0*(WW*64) + j16, r1 = cy1*(WW*64) + j16;
            o00a[v] = r0 + cx0*64; o10a[v] = r0 + cx1*64;
            o01a[v] = r1 + cx0*64; o11a[v] = r1 + cx1*64;
        }

        // ---- all 16 gathers in flight ----
        h8 g00[VV], g10[VV], g01[VV], g11[VV];
        #pragma unroll
        for (int v=0; v<VV; v++) {
            g00[v] = *(const h8*)(vbase[v] + o00a[v]);
            g10[v] = *(const h8*)(vbase[v] + o10a[v]);
            g01[v] = *(const h8*)(vbase[v] + o01a[v]);
            g11[v] = *(const h8*)(vbase[v] + o11a[v]);
        }

        // ---- blends (packed fp16) + dot/norm ----
        float dtv[VV], nmv[VV];
        #pragma unroll
        for (int v=0; v<VV; v++) {
            h2 w00v = bcast_h2(w00a[v]), w10v = bcast_h2(w10a[v]);
            h2 w01v = bcast_h2(w01a[v]), w11v = bcast_h2(w11a[v]);
            float dt = 0.f, nm = 0.f;
            #pragma unroll
            for (int i=0; i<4; i++) {
                h2 a = get2(g00[v],i) * w00v;
                a += get2(g10[v],i) * w10v;
                a += get2(g01[v],i) * w01v;
                a += get2(g11[v],i) * w11v;
                dt = FDOT2(get2(rfv,i), a, dt);
                nm = FDOT2(a, a, nm);
            }
            dtv[v] = dt; nmv[v] = nm;
        }

        // ---- batched quad reductions ----
        #pragma unroll
        for (int v=0; v<VV; v++) {
            dtv[v] += __shfl_xor(dtv[v], 1);
            nmv[v] += __shfl_xor(nmv[v], 1);
        }
        #pragma unroll
        for (int v=0; v<VV; v++) {
            dtv[v] += __shfl_xor(dtv[v], 2);
            nmv[v] += __shfl_xor(nmv[v], 2);
        }
        float cost = 0.f;
        #pragma unroll
        for (int v=0; v<VV; v++) {
            cost += vmask[v] * dtv[v] * __builtin_amdgcn_rsqf(fmaxf(nmv[v], 1e-24f));
        }

        if (j == 0)      *(float*)((char*)out + (d*(HWHW*4) + n*4)) = cost * (1.0f/(float)VV);
        else if (j == 1) *(float*)((char*)out + ((NDB+d)*(HWHW*4) + n*4)) = __builtin_amdgcn_rcpf(invd);
    }
}

// f32 fallback (no workspace): strided gathers from original layout.
__global__ __launch_bounds__(256) void cost_volume_fallback(
        const float* __restrict__ srcp,  // (V,C,HW)
        const float* __restrict__ refp,  // (C,HW)
        const float* __restrict__ cw,
        float* __restrict__ out) {
    int n = blockIdx.x * 256 + threadIdx.x;
    int d = blockIdx.y;
    if (n >= HWHW) return;
    float px = (float)(n % WW), py = (float)(n / WW);

    float rx = cw[0]*px + cw[1]*py + cw[2];
    float ry = cw[3]*px + cw[4]*py + cw[5];
    float rz = cw[6]*px + cw[7]*py + cw[8];

    const float invmin = 1.0f/DMAX;
    const float step = (1.0f/DMIN - 1.0f/DMAX) / (float)(NDB-1);
    float invd = invmin + step * (float)d;
    float depth = 1.0f / invd;

    float rf[CC];
    float ss = 0.f;
    #pragma unroll
    for (int c=0; c<CC; c++) { float x = refp[(size_t)c*HWHW + n]; rf[c]=x; ss += x*x; }
    float inv = 1.0f / fmaxf(sqrtf(ss), 1e-12f);
    #pragma unroll
    for (int c=0; c<CC; c++) rf[c] *= inv;

    float cost = 0.f;
    #pragma unroll
    for (int v=0; v<VV; v++) {
        const float* o = cw + 16 + v*16;
        float mx = o[0]*rx + o[1]*ry + o[2]*rz;
        float my = o[3]*rx + o[4]*ry + o[5]*rz;
        float mz = o[6]*rx + o[7]*ry + o[8]*rz;
        float X = depth*mx + o[9];
        float Y = depth*my + o[10];
        float Zraw = depth*mz + o[11];
        float Z = fmaxf(Zraw, 1e-6f);
        float u  = o[12]*(X/Z) + o[14];
        float vv = o[13]*(Y/Z) + o[15];
        float gx = 2.0f*(u/(float)(WW-1)) - 1.0f;
        float gy = 2.0f*(vv/(float)(HH-1)) - 1.0f;
        bool valid = (gx >= -1.0f) && (gx <= 1.0f) && (gy >= -1.0f) && (gy <= 1.0f) && (Zraw > 1e-6f);

        float x0f = floorf(u), y0f = floorf(vv);
        float wx1 = u - x0f,  wy1 = vv - y0f;
        float wx0 = 1.0f - wx1, wy0 = 1.0f - wy1;
        int x0 = (int)x0f, y0 = (int)y0f;
        int x1 = x0 + 1,   y1 = y0 + 1;

        float m00 = (x0>=0 && x0<WW && y0>=0 && y0<HH) ? 1.f : 0.f;
        float m10 = (x1>=0 && x1<WW && y0>=0 && y0<HH) ? 1.f : 0.f;
        float m01 = (x0>=0 && x0<WW && y1>=0 && y1<HH) ? 1.f : 0.f;
        float m11 = (x1>=0 && x1<WW && y1>=0 && y1<HH) ? 1.f : 0.f;
        float w00 = wx0*wy0*m00, w10 = wx1*wy0*m10;
        float w01 = wx0*wy1*m01, w11 = wx1*wy1*m11;

        int cx0 = min(max(x0,0),WW-1), cx1 = min(max(x1,0),WW-1);
        int cy0 = min(max(y0,0),HH-1), cy1 = min(max(y1,0),HH-1);
        int i00 = cy0*WW+cx0, i10 = cy0*WW+cx1;
        int i01 = cy1*WW+cx0, i11 = cy1*WW+cx1;

        float dot = 0.f, nrm = 0.f;
        const float* basep = srcp + (size_t)v*CC*HWHW;
        #pragma unroll
        for (int c=0; c<CC; c++) {
            const float* pc = basep + (size_t)c*HWHW;
            float wcv = w00*pc[i00] + w10*pc[i10] + w01*pc[i01] + w11*pc[i11];
            dot += rf[c]*wcv;
            nrm += wcv*wcv;
        }
        float sim = dot / fmaxf(sqrtf(nrm), 1e-12f);
        cost += valid ? sim : 0.f;
    }

    out[(size_t)d*HWHW + n] = cost * (1.0f/(float)VV);
    out[(size_t)NDB*HWHW + (size_t)d*HWHW + n] = depth;
}

extern "C" void kernel_launch(void* const* d_in, const int* in_sizes, int n_in,
                              void* d_out, int out_size, void* d_ws, size_t ws_size,
                              hipStream_t stream) {
    const float* ref_feat  = (const float*)d_in[0];
    const float* src_feats = (const float*)d_in[1];
    const float* K_ref     = (const float*)d_in[2];
    const float* c2w_ref   = (const float*)d_in[3];
    const float* K_srcs    = (const float*)d_in[4];
    const float* c2w_srcs  = (const float*)d_in[5];
    float* out = (float*)d_out;
    float* ws  = (float*)d_ws;

    size_t need_bytes = (size_t)CONST_FLOATS*sizeof(float)
                      + (size_t)(VV+1)*HWHW*CC*sizeof(_Float16);

    if (ws_size >= need_bytes) {
        _Float16* srcT = (_Float16*)(ws + CONST_FLOATS);
        _Float16* refT = srcT + (size_t)VV*HWHW*CC;
        prepass<<<((VV+1)*HWHW + 255)/256, 256, 0, stream>>>(
            src_feats, ref_feat, K_ref, c2w_ref, K_srcs, c2w_srcs, srcT, refT, ws);
        // 320 strips x 8 depth-quads, XCD-swizzled
        cost_volume_quad<<<(HWHW/64)*(NDB/DPT), 256, 0, stream>>>(srcT, refT, ws, out);
    } else {
        prepass<<<1, 1, 0, stream>>>(
            src_feats, ref_feat, K_ref, c2w_ref, K_srcs, c2w_srcs,
            (_Float16*)ws, (_Float16*)ws, ws);  // only gid==0 setup matters
        dim3 grid(HWHW/256, NDB);
        cost_volume_fallback<<<grid, 256, 0, stream>>>(src_feats, ref_feat, ws, out);
    }
}